// Round 16
// baseline (120.553 us; speedup 1.0000x reference)
//
#include <hip/hip_runtime.h>

#define LOG2E    1.4426950408889634f
#define TWOLOG2E 2.8853900817779268f
#define NBLK 512u

// ---------------------------------------------------------------------------
// One fused kernel, 512 blocks x 256 threads (2 blocks/CU co-resident: LDS
// 33.8KB, __launch_bounds__(256,2)).  Ledger (R6+R15): phase cores sum to
// ~15.6us; the 3-kernel pipeline pays ~17us in launch + cross-XCD L2
// writeback/invalidate boundaries.  Fusion removes 2 boundaries.
// Barrier: R6 failed on RMW-poll congestion, R7 on ACQUIRE-poll invalidate
// storms.  This version polls with RELAXED atomic loads (plain uncached
// reads, no cache ops), one poller per block, s_sleep(8) backoff.
//
// Phase 1: proj   (R13) -> eq = exp(2*q@Wq^T), ek = exp(2*k@Wk^T)
// Phase 2: scoreP (R13) -> P = exp(score) via eq*ek + column partials Zpart
// Phase 3: pv     (R13) -> out = (P/Z) @ V
// ---------------------------------------------------------------------------

__device__ __forceinline__ void grid_barrier(unsigned* ctr, unsigned* flag)
{
    __syncthreads();
    if (threadIdx.x == 0) {
        __threadfence();                                   // release my writes
        unsigned old = __hip_atomic_fetch_add(ctr, 1u, __ATOMIC_RELAXED,
                                              __HIP_MEMORY_SCOPE_AGENT);
        if (old == NBLK - 1u) {
            __hip_atomic_store(flag, 1u, __ATOMIC_RELAXED,
                               __HIP_MEMORY_SCOPE_AGENT);
        } else {
            while (__hip_atomic_load(flag, __ATOMIC_RELAXED,
                                     __HIP_MEMORY_SCOPE_AGENT) == 0u)
                __builtin_amdgcn_s_sleep(8);               // ~512 cyc backoff
        }
        __threadfence();                                   // acquire others'
    }
    __syncthreads();
}

__global__ __launch_bounds__(256, 2) void mega_kernel(
    const float* __restrict__ queries, const float* __restrict__ keys,
    const float* __restrict__ values,
    const float* __restrict__ Wq, const float* __restrict__ Wk,
    const float* __restrict__ wv,
    float* __restrict__ out,
    float* __restrict__ eq, float* __restrict__ ek,
    float* __restrict__ P, float* __restrict__ Zpart,
    unsigned* __restrict__ bar)
{
    __shared__ float smem[8448];       // 33.8 KB, reused across phases
    const int t   = threadIdx.x;
    const int bid = blockIdx.x;

    // ======================= Phase 1: proj (R13) ========================
    {
        float* xs = smem;              // [8][128]
        const int isK = bid >= 256;
        const int rowBase = (bid & 255) * 8;
        const float* __restrict__ x = isK ? keys : queries;
        const float* __restrict__ W = isK ? Wk : Wq;
        float* __restrict__ op = isK ? ek : eq;

        ((float4*)xs)[t] = ((const float4*)(x + (size_t)rowBase * 128))[t];
        __syncthreads();

        const int h  = t & 127;
        const int rh = t >> 7;
        const float4* wrow = (const float4*)(W + (size_t)h * 128);
        float acc[4] = {0.f, 0.f, 0.f, 0.f};

        #pragma unroll 4
        for (int d4 = 0; d4 < 32; ++d4) {
            float4 w = wrow[d4];
            #pragma unroll
            for (int r = 0; r < 4; ++r) {
                float4 xv = *(const float4*)&xs[(rh * 4 + r) * 128 + d4 * 4];
                acc[r] = fmaf(xv.x, w.x, acc[r]);
                acc[r] = fmaf(xv.y, w.y, acc[r]);
                acc[r] = fmaf(xv.z, w.z, acc[r]);
                acc[r] = fmaf(xv.w, w.w, acc[r]);
            }
        }
        #pragma unroll
        for (int r = 0; r < 4; ++r)
            op[(size_t)(rowBase + rh * 4 + r) * 128 + h] =
                __builtin_amdgcn_exp2f(acc[r] * TWOLOG2E);
    }

    grid_barrier(bar, bar + 16);

    // ======================= Phase 2: scoreP (R13) ======================
    {
        float* qs    = smem;           // [32][130]
        float* ks_   = smem + 4160;    // [32][130]
        float* part2 = smem + 8320;    // [4][32]

        const int kt = bid & 7, qt = (bid >> 3) & 7, b = bid >> 6;

        const float4* qsrc = (const float4*)(eq + (size_t)(b * 256 + qt * 32) * 128);
        const float4* ksrc = (const float4*)(ek + (size_t)(b * 256 + kt * 32) * 128);
        {
            int r = t >> 3, c = (t & 7) * 16;
            #pragma unroll
            for (int j = 0; j < 4; ++j) {
                float4 v  = qsrc[t * 4 + j];
                *(float4*)&qs[r * 130 + c + j * 4] = v;
                float4 v2 = ksrc[t * 4 + j];
                *(float4*)&ks_[r * 130 + c + j * 4] = v2;
            }
        }
        __syncthreads();

        const int lk = (t & 15) * 2;
        const int lq = (t >> 4) * 2;

        float a00 = 0.f, a01 = 0.f, a10 = 0.f, a11 = 0.f;
        float wsum = 0.f;

        #pragma unroll 4
        for (int h = 0; h < 128; h += 4) {
            float4 w4 = *(const float4*)&wv[h];          // uniform -> s_load
            wsum += (w4.x + w4.y) + (w4.z + w4.w);
            float4 qa = *(const float4*)&qs[lq * 130 + h];
            float4 qb = *(const float4*)&qs[(lq + 1) * 130 + h];
            float4 ka = *(const float4*)&ks_[lk * 130 + h];
            float4 kb = *(const float4*)&ks_[(lk + 1) * 130 + h];
            const float wj[4]  = {w4.x, w4.y, w4.z, w4.w};
            const float qaj[4] = {qa.x, qa.y, qa.z, qa.w};
            const float qbj[4] = {qb.x, qb.y, qb.z, qb.w};
            const float kaj[4] = {ka.x, ka.y, ka.z, ka.w};
            const float kbj[4] = {kb.x, kb.y, kb.z, kb.w};
            #pragma unroll
            for (int j = 0; j < 4; ++j) {
                float r00 = __builtin_amdgcn_rcpf(fmaf(qaj[j], kaj[j], 1.0f));
                float r01 = __builtin_amdgcn_rcpf(fmaf(qaj[j], kbj[j], 1.0f));
                float r10 = __builtin_amdgcn_rcpf(fmaf(qbj[j], kaj[j], 1.0f));
                float r11 = __builtin_amdgcn_rcpf(fmaf(qbj[j], kbj[j], 1.0f));
                a00 = fmaf(wj[j], r00, a00);
                a01 = fmaf(wj[j], r01, a01);
                a10 = fmaf(wj[j], r10, a10);
                a11 = fmaf(wj[j], r11, a11);
            }
        }

        const float wsl = wsum * LOG2E;
        const float M2L = -2.0f * LOG2E;
        float p00 = __builtin_amdgcn_exp2f(fmaf(M2L, a00, wsl));
        float p01 = __builtin_amdgcn_exp2f(fmaf(M2L, a01, wsl));
        float p10 = __builtin_amdgcn_exp2f(fmaf(M2L, a10, wsl));
        float p11 = __builtin_amdgcn_exp2f(fmaf(M2L, a11, wsl));

        const int q = qt * 32 + lq;
        const int k = kt * 32 + lk;
        *(float2*)&P[((size_t)(b * 256 + q)) * 256 + k]     = make_float2(p00, p01);
        *(float2*)&P[((size_t)(b * 256 + q + 1)) * 256 + k] = make_float2(p10, p11);

        float sa = p00 + p10;
        float sb = p01 + p11;
        sa += __shfl_xor(sa, 16, 64);
        sa += __shfl_xor(sa, 32, 64);
        sb += __shfl_xor(sb, 16, 64);
        sb += __shfl_xor(sb, 32, 64);
        const int wid = t >> 6;
        if ((t & 63) < 16) {
            part2[wid * 32 + lk]     = sa;
            part2[wid * 32 + lk + 1] = sb;
        }
        __syncthreads();
        if (t < 32) {
            float z = part2[t] + part2[32 + t] + part2[64 + t] + part2[96 + t];
            Zpart[(size_t)b * 2048 + qt * 256 + kt * 32 + t] = z;
        }
    }

    grid_barrier(bar + 32, bar + 48);

    // ======================= Phase 3: pv (R13) ==========================
    {
        float* ps  = smem;             // [4][260]
        float* red = smem + 1040;      // [4][512]
        const int b  = bid >> 6;
        const int q0 = (bid & 63) * 4;

        {
            const int q = t >> 6;
            const int k = (t & 63) * 4;
            const float* zb = Zpart + (size_t)b * 2048 + k;
            float4 z = make_float4(0.f, 0.f, 0.f, 0.f);
            #pragma unroll
            for (int qt = 0; qt < 8; ++qt) {
                float4 a = *(const float4*)(zb + qt * 256);
                z.x += a.x; z.y += a.y; z.z += a.z; z.w += a.w;
            }
            const float* prow = P + ((size_t)(b * 256 + q0 + q)) * 256 + k;
            float4 s = *(const float4*)prow;
            float4 r;
            r.x = s.x * __builtin_amdgcn_rcpf(z.x);
            r.y = s.y * __builtin_amdgcn_rcpf(z.y);
            r.z = s.z * __builtin_amdgcn_rcpf(z.z);
            r.w = s.w * __builtin_amdgcn_rcpf(z.w);
            *(float4*)&ps[q * 260 + k] = r;
        }
        __syncthreads();

        const int wid  = t >> 6;
        const int lane = t & 63;
        const float* vb = values + (size_t)b * 256 * 128 + lane * 2;

        float ax[4] = {0.f, 0.f, 0.f, 0.f};
        float ay[4] = {0.f, 0.f, 0.f, 0.f};

        for (int kk4 = wid * 16; kk4 < wid * 16 + 16; ++kk4) {
            float4 p0 = *(const float4*)&ps[0 * 260 + kk4 * 4];
            float4 p1 = *(const float4*)&ps[1 * 260 + kk4 * 4];
            float4 p2 = *(const float4*)&ps[2 * 260 + kk4 * 4];
            float4 p3 = *(const float4*)&ps[3 * 260 + kk4 * 4];
            #pragma unroll
            for (int u = 0; u < 4; ++u) {
                int kk = kk4 * 4 + u;
                float2 v = *(const float2*)(vb + (size_t)kk * 128);
                float f0 = (&p0.x)[u], f1 = (&p1.x)[u], f2 = (&p2.x)[u], f3 = (&p3.x)[u];
                ax[0] = fmaf(f0, v.x, ax[0]); ay[0] = fmaf(f0, v.y, ay[0]);
                ax[1] = fmaf(f1, v.x, ax[1]); ay[1] = fmaf(f1, v.y, ay[1]);
                ax[2] = fmaf(f2, v.x, ax[2]); ay[2] = fmaf(f2, v.y, ay[2]);
                ax[3] = fmaf(f3, v.x, ax[3]); ay[3] = fmaf(f3, v.y, ay[3]);
            }
        }

        #pragma unroll
        for (int q = 0; q < 4; ++q)
            *(float2*)&red[wid * 512 + q * 128 + lane * 2] = make_float2(ax[q], ay[q]);
        __syncthreads();

        {
            const int j = t * 2;
            float2 s = make_float2(0.f, 0.f);
            #pragma unroll
            for (int w = 0; w < 4; ++w) {
                float2 r = *(const float2*)&red[w * 512 + j];
                s.x += r.x; s.y += r.y;
            }
            const int q = j >> 7, d = j & 127;
            *(float2*)&out[((size_t)(b * 256 + q0 + q)) * 128 + d] = s;
        }
    }
}

// ---------------------------------------------------------------------------
extern "C" void kernel_launch(void* const* d_in, const int* in_sizes, int n_in,
                              void* d_out, int out_size, void* d_ws, size_t ws_size,
                              hipStream_t stream)
{
    const float* queries = (const float*)d_in[0];  // (8,256,128)
    const float* keys    = (const float*)d_in[1];  // (8,256,128)
    const float* values  = (const float*)d_in[2];  // (8,256,128)
    const float* Wq      = (const float*)d_in[3];  // (128,128)
    const float* Wk      = (const float*)d_in[4];  // (128,128)
    const float* wv      = (const float*)d_in[5];  // (128,)
    float* out = (float*)d_out;                    // (8,256,128)

    float* ws = (float*)d_ws;
    float* eqb   = ws;                   // 262144 floats  e^{2*qproj}
    float* ekb   = ws + 262144;          // 262144 floats  e^{2*kproj}
    float* P     = ws + 524288;          // 524288 floats  exp(score)
    float* Zpart = ws + 1048576;         // 16384 floats
    unsigned* bar = (unsigned*)(ws + 1048576 + 16384);  // ctr/flag pairs

    hipMemsetAsync(bar, 0, 64 * sizeof(unsigned), stream);
    mega_kernel<<<NBLK, 256, 0, stream>>>(queries, keys, values, Wq, Wk, wv,
                                          out, eqb, ekb, P, Zpart, bar);
}

// Round 17
// 31.800 us; speedup vs baseline: 3.7910x; 3.7910x over previous
//
#include <hip/hip_runtime.h>
#include <hip/hip_fp16.h>

#define LOG2E    1.4426950408889634f
#define TWOLOG2E 2.8853900817779268f

// ---------------------------------------------------------------------------
// 3-launch pipeline (R13 structure), intermediates compressed to fp16 to
// halve boundary-crossing traffic (eq/ek/P: 6MB -> 3MB).  P carries a -0.5
// log2-shift so max |score| (<=11.31 nats) stays under fp16 max; softmax is
// shift-invariant and Zpart sums the same shifted values, so it cancels.
//   K1 proj   -> eq = fp16(exp(2*q@Wq^T)), ek likewise
//   K2 scoreP -> P = fp16(exp2(score*log2e - 0.5)) + fp32 column partials
//   K3 pv     -> out = (P/Z) @ V
// ---------------------------------------------------------------------------

// Kernel 1: projections -> fp16 exponentials. 512 blocks, 256 thr, 8 rows/blk.
__global__ __launch_bounds__(256) void proj_kernel(
    const float* __restrict__ queries, const float* __restrict__ keys,
    const float* __restrict__ Wq, const float* __restrict__ Wk,
    __half* __restrict__ eq, __half* __restrict__ ek)
{
    __shared__ float xs[8 * 128];
    const int isK = blockIdx.x >= 256;
    const int rowBase = (blockIdx.x & 255) * 8;
    const float* __restrict__ x = isK ? keys : queries;
    const float* __restrict__ W = isK ? Wk : Wq;
    __half* __restrict__ op = isK ? ek : eq;
    const int t = threadIdx.x;

    ((float4*)xs)[t] = ((const float4*)(x + (size_t)rowBase * 128))[t];
    __syncthreads();

    const int h  = t & 127;
    const int rh = t >> 7;
    const float4* wrow = (const float4*)(W + (size_t)h * 128);
    float acc[4] = {0.f, 0.f, 0.f, 0.f};

    #pragma unroll 4
    for (int d4 = 0; d4 < 32; ++d4) {
        float4 w = wrow[d4];
        #pragma unroll
        for (int r = 0; r < 4; ++r) {
            float4 xv = *(const float4*)&xs[(rh * 4 + r) * 128 + d4 * 4];
            acc[r] = fmaf(xv.x, w.x, acc[r]);
            acc[r] = fmaf(xv.y, w.y, acc[r]);
            acc[r] = fmaf(xv.z, w.z, acc[r]);
            acc[r] = fmaf(xv.w, w.w, acc[r]);
        }
    }
    #pragma unroll
    for (int r = 0; r < 4; ++r)      // coalesced 2B stores (512B/wave)
        op[(size_t)(rowBase + rh * 4 + r) * 128 + h] =
            __float2half(__builtin_amdgcn_exp2f(acc[r] * TWOLOG2E));
}

// Kernel 2: scoreP. P = exp2(log2e*score - 0.5) in fp16; Zpart fp32.
#define LDP 130

__global__ __launch_bounds__(256) void scoreP_kernel(
    const __half* __restrict__ eq, const __half* __restrict__ ek,
    const float* __restrict__ wv, __half* __restrict__ P,
    float* __restrict__ Zpart)
{
    __shared__ float qs[32 * LDP];
    __shared__ float ks_[32 * LDP];
    __shared__ float part2[4][32];

    const int kt = blockIdx.x, qt = blockIdx.y, b = blockIdx.z;
    const int t = threadIdx.x;

    // stage fp16 -> fp32 LDS (16 elems per thread per array)
    {
        const int r = t >> 3, c = (t & 7) * 16;
        const __half2* qh = (const __half2*)(eq + (size_t)(b * 256 + qt * 32 + r) * 128 + c);
        const __half2* kh = (const __half2*)(ek + (size_t)(b * 256 + kt * 32 + r) * 128 + c);
        #pragma unroll
        for (int j = 0; j < 8; ++j) {
            float2 fq = __half22float2(qh[j]);
            float2 fk = __half22float2(kh[j]);
            *(float2*)&qs[r * LDP + c + 2 * j]  = fq;
            *(float2*)&ks_[r * LDP + c + 2 * j] = fk;
        }
    }
    __syncthreads();

    const int lk = (t & 15) * 2;
    const int lq = (t >> 4) * 2;

    float a00 = 0.f, a01 = 0.f, a10 = 0.f, a11 = 0.f;
    float wsum = 0.f;

    #pragma unroll 4
    for (int h = 0; h < 128; h += 4) {
        float4 w4 = *(const float4*)&wv[h];          // uniform -> s_load
        wsum += (w4.x + w4.y) + (w4.z + w4.w);
        float4 qa = *(const float4*)&qs[lq * LDP + h];
        float4 qb = *(const float4*)&qs[(lq + 1) * LDP + h];
        float4 ka = *(const float4*)&ks_[lk * LDP + h];
        float4 kb = *(const float4*)&ks_[(lk + 1) * LDP + h];
        const float wj[4]  = {w4.x, w4.y, w4.z, w4.w};
        const float qaj[4] = {qa.x, qa.y, qa.z, qa.w};
        const float qbj[4] = {qb.x, qb.y, qb.z, qb.w};
        const float kaj[4] = {ka.x, ka.y, ka.z, ka.w};
        const float kbj[4] = {kb.x, kb.y, kb.z, kb.w};
        #pragma unroll
        for (int j = 0; j < 4; ++j) {
            float r00 = __builtin_amdgcn_rcpf(fmaf(qaj[j], kaj[j], 1.0f));
            float r01 = __builtin_amdgcn_rcpf(fmaf(qaj[j], kbj[j], 1.0f));
            float r10 = __builtin_amdgcn_rcpf(fmaf(qbj[j], kaj[j], 1.0f));
            float r11 = __builtin_amdgcn_rcpf(fmaf(qbj[j], kbj[j], 1.0f));
            a00 = fmaf(wj[j], r00, a00);
            a01 = fmaf(wj[j], r01, a01);
            a10 = fmaf(wj[j], r10, a10);
            a11 = fmaf(wj[j], r11, a11);
        }
    }

    // p = exp2(log2e*(wsum - 2a) - 0.5)   [-0.5: fp16 overflow headroom]
    const float wsl = fmaf(wsum, LOG2E, -0.5f);
    const float M2L = -2.0f * LOG2E;
    float p00 = __builtin_amdgcn_exp2f(fmaf(M2L, a00, wsl));
    float p01 = __builtin_amdgcn_exp2f(fmaf(M2L, a01, wsl));
    float p10 = __builtin_amdgcn_exp2f(fmaf(M2L, a10, wsl));
    float p11 = __builtin_amdgcn_exp2f(fmaf(M2L, a11, wsl));

    const int q = qt * 32 + lq;
    const int k = kt * 32 + lk;
    *(__half2*)&P[((size_t)(b * 256 + q)) * 256 + k]     = __floats2half2_rn(p00, p01);
    *(__half2*)&P[((size_t)(b * 256 + q + 1)) * 256 + k] = __floats2half2_rn(p10, p11);

    float sa = p00 + p10;
    float sb = p01 + p11;
    sa += __shfl_xor(sa, 16, 64);
    sa += __shfl_xor(sa, 32, 64);
    sb += __shfl_xor(sb, 16, 64);
    sb += __shfl_xor(sb, 32, 64);
    const int wid = t >> 6;
    if ((t & 63) < 16) {
        part2[wid][lk]     = sa;
        part2[wid][lk + 1] = sb;
    }
    __syncthreads();
    if (t < 32) {
        float z = part2[0][t] + part2[1][t] + part2[2][t] + part2[3][t];
        Zpart[(size_t)b * 2048 + qt * 256 + kt * 32 + t] = z;
    }
}

// Kernel 3: pv. P read as fp16; math in fp32 (verbatim R13 otherwise).
__global__ __launch_bounds__(256) void pv_kernel(
    const __half* __restrict__ P, const float* __restrict__ Zpart,
    const float* __restrict__ values, float* __restrict__ out)
{
    __shared__ float ps[4 * 260];
    __shared__ float red[4 * 512];
    const int b  = blockIdx.x >> 6;
    const int q0 = (blockIdx.x & 63) * 4;
    const int t  = threadIdx.x;

    {
        const int q = t >> 6;
        const int k = (t & 63) * 4;
        const float* zb = Zpart + (size_t)b * 2048 + k;
        float4 z = make_float4(0.f, 0.f, 0.f, 0.f);
        #pragma unroll
        for (int qt = 0; qt < 8; ++qt) {
            float4 a = *(const float4*)(zb + qt * 256);
            z.x += a.x; z.y += a.y; z.z += a.z; z.w += a.w;
        }
        const __half* prow = P + ((size_t)(b * 256 + q0 + q)) * 256 + k;
        float2 s0 = __half22float2(*(const __half2*)(prow));
        float2 s1 = __half22float2(*(const __half2*)(prow + 2));
        float4 r;
        r.x = s0.x * __builtin_amdgcn_rcpf(z.x);
        r.y = s0.y * __builtin_amdgcn_rcpf(z.y);
        r.z = s1.x * __builtin_amdgcn_rcpf(z.z);
        r.w = s1.y * __builtin_amdgcn_rcpf(z.w);
        *(float4*)&ps[q * 260 + k] = r;
    }
    __syncthreads();

    const int wid  = t >> 6;
    const int lane = t & 63;
    const float* vb = values + (size_t)b * 256 * 128 + lane * 2;

    float ax[4] = {0.f, 0.f, 0.f, 0.f};
    float ay[4] = {0.f, 0.f, 0.f, 0.f};

    for (int kk4 = wid * 16; kk4 < wid * 16 + 16; ++kk4) {
        float4 p0 = *(const float4*)&ps[0 * 260 + kk4 * 4];
        float4 p1 = *(const float4*)&ps[1 * 260 + kk4 * 4];
        float4 p2 = *(const float4*)&ps[2 * 260 + kk4 * 4];
        float4 p3 = *(const float4*)&ps[3 * 260 + kk4 * 4];
        #pragma unroll
        for (int u = 0; u < 4; ++u) {
            int kk = kk4 * 4 + u;
            float2 v = *(const float2*)(vb + (size_t)kk * 128);
            float f0 = (&p0.x)[u], f1 = (&p1.x)[u], f2 = (&p2.x)[u], f3 = (&p3.x)[u];
            ax[0] = fmaf(f0, v.x, ax[0]); ay[0] = fmaf(f0, v.y, ay[0]);
            ax[1] = fmaf(f1, v.x, ax[1]); ay[1] = fmaf(f1, v.y, ay[1]);
            ax[2] = fmaf(f2, v.x, ax[2]); ay[2] = fmaf(f2, v.y, ay[2]);
            ax[3] = fmaf(f3, v.x, ax[3]); ay[3] = fmaf(f3, v.y, ay[3]);
        }
    }

    #pragma unroll
    for (int q = 0; q < 4; ++q)
        *(float2*)&red[wid * 512 + q * 128 + lane * 2] = make_float2(ax[q], ay[q]);
    __syncthreads();

    {
        const int j = t * 2;
        float2 s = make_float2(0.f, 0.f);
        #pragma unroll
        for (int w = 0; w < 4; ++w) {
            float2 r = *(const float2*)&red[w * 512 + j];
            s.x += r.x; s.y += r.y;
        }
        const int q = j >> 7, d = j & 127;
        *(float2*)&out[((size_t)(b * 256 + q0 + q)) * 128 + d] = s;
    }
}

// ---------------------------------------------------------------------------
extern "C" void kernel_launch(void* const* d_in, const int* in_sizes, int n_in,
                              void* d_out, int out_size, void* d_ws, size_t ws_size,
                              hipStream_t stream)
{
    const float* queries = (const float*)d_in[0];  // (8,256,128)
    const float* keys    = (const float*)d_in[1];  // (8,256,128)
    const float* values  = (const float*)d_in[2];  // (8,256,128)
    const float* Wq      = (const float*)d_in[3];  // (128,128)
    const float* Wk      = (const float*)d_in[4];  // (128,128)
    const float* wv      = (const float*)d_in[5];  // (128,)
    float* out = (float*)d_out;                    // (8,256,128)

    float* ws = (float*)d_ws;
    __half* eqb  = (__half*)ws;              // 262144 halves (512KB)
    __half* ekb  = (__half*)(ws + 131072);   // 262144 halves (512KB)
    __half* P    = (__half*)(ws + 262144);   // 524288 halves (1MB)
    float* Zpart = ws + 524288;              // 16384 floats

    proj_kernel<<<512, 256, 0, stream>>>(queries, keys, Wq, Wk, eqb, ekb);
    scoreP_kernel<<<dim3(8, 8, 8), 256, 0, stream>>>(eqb, ekb, wv, P, Zpart);
    pv_kernel<<<512, 256, 0, stream>>>(P, Zpart, values, out);
}